// Round 8
// baseline (364.053 us; speedup 1.0000x reference)
//
#include <hip/hip_runtime.h>

#define N_NODES  100000
#define N_EDGES  1600000
#define N_GRAPHS 256
#define F        64

#define BSHIFT   8
#define BNODES   256                          // nodes per bucket
#define NBUCKET  391                          // ceil(N_NODES / 256)
#define CHUNK    8192
#define NCHUNK   196                          // ceil(N_EDGES / CHUNK)

// ---------- K1: per-chunk bucket histogram (LDS atomics only) ----------
__global__ __launch_bounds__(1024) void hist_kernel(
        const int* __restrict__ dst, int* __restrict__ cnt) {
    __shared__ int hist[NBUCKET];
    int tid = threadIdx.x;
    for (int b = tid; b < NBUCKET; b += 1024) hist[b] = 0;
    __syncthreads();
    int base = blockIdx.x * CHUNK;
    int end  = min(base + CHUNK, N_EDGES);
    for (int e = base + tid; e < end; e += 1024)
        atomicAdd(&hist[dst[e] >> BSHIFT], 1);
    __syncthreads();
    for (int b = tid; b < NBUCKET; b += 1024)
        cnt[blockIdx.x * NBUCKET + b] = hist[b];
}

// ---------- K2: global slot starts per (chunk,bucket) + bucket bases ----------
__global__ __launch_bounds__(512) void chunk_scan_kernel(
        const int* __restrict__ cnt, int* __restrict__ start, int* __restrict__ bbase) {
    __shared__ int t[512];
    int b = threadIdx.x;
    int tot = 0;
    if (b < NBUCKET)
        for (int c = 0; c < NCHUNK; ++c) tot += cnt[c * NBUCKET + b];  // coalesced
    t[b] = (b < NBUCKET) ? tot : 0;
    __syncthreads();
    #pragma unroll
    for (int o = 1; o < 512; o <<= 1) {           // inclusive scan
        int u = (b >= o) ? t[b - o] : 0;
        __syncthreads();
        t[b] += u;
        __syncthreads();
    }
    if (b < NBUCKET) {
        int base = t[b] - tot;                    // exclusive
        bbase[b] = base;
        if (b == NBUCKET - 1) bbase[NBUCKET] = t[b];
        int run = base;
        for (int c = 0; c < NCHUNK; ++c) {
            start[c * NBUCKET + b] = run;         // coalesced
            run += cnt[c * NBUCKET + b];
        }
    }
}

// ---------- K3: bucket-partitioned scatter of packed (dstLocal<<17 | src) ----------
__global__ __launch_bounds__(1024) void scatter_kernel(
        const int* __restrict__ src, const int* __restrict__ dst,
        const int* __restrict__ start, unsigned int* __restrict__ pairs) {
    __shared__ int cur[NBUCKET];
    int tid = threadIdx.x;
    for (int b = tid; b < NBUCKET; b += 1024)
        cur[b] = start[blockIdx.x * NBUCKET + b];
    __syncthreads();
    int base = blockIdx.x * CHUNK;
    int end  = min(base + CHUNK, N_EDGES);
    for (int e = base + tid; e < end; e += 1024) {
        int d = dst[e];
        int slot = atomicAdd(&cur[d >> BSHIFT], 1);
        pairs[slot] = ((unsigned)(d & (BNODES - 1)) << 17) | (unsigned)src[e];
    }
}

// ---------- K4: per-bucket counting sort -> CSR (eidx sorted by dst, noff) ----------
__global__ __launch_bounds__(1024) void bucket_sort_kernel(
        const unsigned int* __restrict__ pairs,
        const int* __restrict__ bbase,
        int* __restrict__ eidx, int* __restrict__ noff) {
    __shared__ int cnt[BNODES];
    __shared__ int pref[BNODES];
    __shared__ int cur[BNODES];
    int tid = threadIdx.x;
    int b = blockIdx.x;
    int lo = bbase[b], hi = bbase[b + 1];

    if (tid < BNODES) cnt[tid] = 0;
    __syncthreads();
    for (int e = lo + tid; e < hi; e += 1024)
        atomicAdd(&cnt[pairs[e] >> 17], 1);
    __syncthreads();
    if (tid < BNODES) pref[tid] = cnt[tid];
    __syncthreads();
    #pragma unroll
    for (int o = 1; o < BNODES; o <<= 1) {
        int u = (tid < BNODES && tid >= o) ? pref[tid - o] : 0;
        __syncthreads();
        if (tid < BNODES) pref[tid] += u;
        __syncthreads();
    }
    if (tid < BNODES) {
        int excl = lo + pref[tid] - cnt[tid];
        cur[tid] = excl;
        int node = b * BNODES + tid;
        if (node < N_NODES) noff[node] = excl;
        if (node == N_NODES - 1) noff[N_NODES] = hi;
    }
    __syncthreads();
    for (int e = lo + tid; e < hi; e += 1024) {
        unsigned int p = pairs[e];
        int slot = atomicAdd(&cur[p >> 17], 1);
        eidx[slot] = (int)(p & 0x1FFFFu);   // writes stay in a 16KB L2-resident window
    }
}

// ---------- K5: fused gather + transform (batched-MLP gather, readlane matmul) ----------
#define GT_BLOCKS 2048
#define GT_WAVES  (GT_BLOCKS * 4)

__global__ __launch_bounds__(256, 6) void gather_transform_kernel(
        const float* __restrict__ x,
        const int*   __restrict__ noff,
        const int*   __restrict__ eidx,
        const float* __restrict__ Wg,   // [64,64] (k, f)
        const float* __restrict__ bg,
        const float* __restrict__ Wa,
        const float* __restrict__ ba,
        float*       __restrict__ h,
        float*       __restrict__ scores) {
    int tid  = threadIdx.x;
    int lane = tid & 63;
    int grp  = lane >> 4;   // 0..3: row within a 4-row gather batch
    int c    = lane & 15;   // float4 chunk within a row
    int waveId = blockIdx.x * 4 + (tid >> 6);

    float wcol[F];
    #pragma unroll
    for (int k = 0; k < F; ++k) wcol[k] = Wg[k * F + lane];
    float bgl = bg[lane];
    float wal = Wa[lane];
    float ba0 = ba[0];

    const float4* x4 = (const float4*)x;

    for (int n = waveId; n < N_NODES; n += GT_WAVES) {
        int start = noff[n];
        int end   = noff[n + 1];

        float4 a = make_float4(0.f, 0.f, 0.f, 0.f);
        for (int base = start; base < end; base += 64) {
            int rem = end - base; if (rem > 64) rem = 64;
            int sl = (base + lane < end) ? eidx[base + lane] : 0;   // coalesced; 0 for OOB
            for (int jj = 0; jj < rem; jj += 16) {
                // issue 4 independent float4 gathers (16 edges) before accumulating
                float4 vb0, vb1, vb2, vb3;
                int e0 = jj + 0  + grp, e1 = jj + 4  + grp;
                int e2 = jj + 8  + grp, e3 = jj + 12 + grp;
                int s0 = __shfl(sl, e0 & 63, 64);
                int s1 = __shfl(sl, e1 & 63, 64);
                int s2 = __shfl(sl, e2 & 63, 64);
                int s3 = __shfl(sl, e3 & 63, 64);
                vb0 = x4[s0 * 16 + c];   // OOB lanes load row 0 (safe, hot line)
                vb1 = x4[s1 * 16 + c];
                vb2 = x4[s2 * 16 + c];
                vb3 = x4[s3 * 16 + c];
                if (e0 < rem) { a.x += vb0.x; a.y += vb0.y; a.z += vb0.z; a.w += vb0.w; }
                if (e1 < rem) { a.x += vb1.x; a.y += vb1.y; a.z += vb1.z; a.w += vb1.w; }
                if (e2 < rem) { a.x += vb2.x; a.y += vb2.y; a.z += vb2.z; a.w += vb2.w; }
                if (e3 < rem) { a.x += vb3.x; a.y += vb3.y; a.z += vb3.z; a.w += vb3.w; }
            }
        }
        #pragma unroll
        for (int o = 16; o <= 32; o <<= 1) {
            a.x += __shfl_xor(a.x, o, 64);
            a.y += __shfl_xor(a.y, o, 64);
            a.z += __shfl_xor(a.z, o, 64);
            a.w += __shfl_xor(a.w, o, 64);
        }
        { float4 v = x4[n * 16 + c]; a.x += v.x; a.y += v.y; a.z += v.z; a.w += v.w; }

        float re[4] = {a.x, a.y, a.z, a.w};
        float acc0 = 0.f, acc1 = 0.f, acc2 = 0.f, acc3 = 0.f;
        #pragma unroll
        for (int k = 0; k < F; k += 4) {
            float r0 = __int_as_float(__builtin_amdgcn_readlane(__float_as_int(re[0]), k >> 2));
            float r1 = __int_as_float(__builtin_amdgcn_readlane(__float_as_int(re[1]), k >> 2));
            float r2 = __int_as_float(__builtin_amdgcn_readlane(__float_as_int(re[2]), k >> 2));
            float r3 = __int_as_float(__builtin_amdgcn_readlane(__float_as_int(re[3]), k >> 2));
            acc0 += r0 * wcol[k + 0];
            acc1 += r1 * wcol[k + 1];
            acc2 += r2 * wcol[k + 2];
            acc3 += r3 * wcol[k + 3];
        }
        float hv = (acc0 + acc1) + (acc2 + acc3) + bgl;
        hv = hv > 0.f ? hv : 0.f;
        h[n * F + lane] = hv;

        float p = hv * wal;
        #pragma unroll
        for (int o = 32; o > 0; o >>= 1)
            p += __shfl_down(p, o, 64);
        if (lane == 0) scores[n] = p + ba0;
    }
}

// ---------- K6: fused segmented softmax + weighted pool (atomic-free, float4) ----------
__device__ __forceinline__ int lower_bound_i(const int* __restrict__ a, int n, int key) {
    int lo = 0, hi = n;
    while (lo < hi) {
        int mid = (lo + hi) >> 1;
        if (a[mid] < key) lo = mid + 1; else hi = mid;
    }
    return lo;
}

#define POOL_THREADS 512
#define POOL_WAVES   (POOL_THREADS / 64)

__global__ __launch_bounds__(POOL_THREADS) void attn_pool_kernel(
        const float* __restrict__ h,
        const float* __restrict__ scores,
        const int*   __restrict__ batch,
        float*       __restrict__ out) {
    int g = blockIdx.x;
    int tid  = threadIdx.x;
    int wave = tid >> 6;
    int lane = tid & 63;
    int grp  = lane >> 4;
    int c    = lane & 15;

    int lo = lower_bound_i(batch, N_NODES, g);
    int hi = lower_bound_i(batch, N_NODES, g + 1);

    __shared__ float red[POOL_THREADS];
    float m = -INFINITY;
    for (int n = lo + tid; n < hi; n += POOL_THREADS) m = fmaxf(m, scores[n]);
    red[tid] = m;
    __syncthreads();
    #pragma unroll
    for (int s = POOL_THREADS / 2; s > 0; s >>= 1) {
        if (tid < s) red[tid] = fmaxf(red[tid], red[tid + s]);
        __syncthreads();
    }
    m = red[0];
    __syncthreads();

    const float4* h4 = (const float4*)h;
    float4 acc = make_float4(0.f, 0.f, 0.f, 0.f);
    float den = 0.f;
    for (int base = lo + wave * 4; base < hi; base += POOL_WAVES * 4) {
        int n = base + grp;
        if (n < hi) {
            float e = __expf(scores[n] - m);
            den += e;
            float4 v = h4[n * 16 + c];
            acc.x += e * v.x; acc.y += e * v.y; acc.z += e * v.z; acc.w += e * v.w;
        }
    }
    #pragma unroll
    for (int o = 16; o <= 32; o <<= 1) {
        acc.x += __shfl_xor(acc.x, o, 64);
        acc.y += __shfl_xor(acc.y, o, 64);
        acc.z += __shfl_xor(acc.z, o, 64);
        acc.w += __shfl_xor(acc.w, o, 64);
        den   += __shfl_xor(den,   o, 64);
    }

    __shared__ float4 accs4[POOL_WAVES][16];
    __shared__ float  dens[POOL_WAVES];
    if (lane < 16) accs4[wave][c] = acc;
    if (lane == 0) dens[wave] = den;
    __syncthreads();

    if (wave == 0) {
        const float* accsf = (const float*)accs4;   // [POOL_WAVES][64]
        float a = 0.f, d = 0.f;
        #pragma unroll
        for (int w = 0; w < POOL_WAVES; ++w) { a += accsf[w * F + lane]; d += dens[w]; }
        out[g * F + lane] = (hi > lo) ? a / d : 0.f;
    }
}

extern "C" void kernel_launch(void* const* d_in, const int* in_sizes, int n_in,
                              void* d_out, int out_size, void* d_ws, size_t ws_size,
                              hipStream_t stream) {
    const float* x     = (const float*)d_in[0];
    const int*   ei    = (const int*)d_in[1];   // [2, N_EDGES]
    const int*   batch = (const int*)d_in[2];   // [N_NODES]
    const float* Wg    = (const float*)d_in[3];
    const float* bg    = (const float*)d_in[4];
    const float* Wa    = (const float*)d_in[5];
    const float* ba    = (const float*)d_in[6];
    float* out = (float*)d_out;

    const int* src = ei;
    const int* dst = ei + N_EDGES;

    // workspace layout (bytes, 256-aligned)
    char* ws = (char*)d_ws;
    int*          cnt    = (int*)(ws);                     // 306,544
    int*          start  = (int*)(ws +   306688);          // 306,544
    int*          bbase  = (int*)(ws +   613376);          // 1,568
    unsigned int* pairs  = (unsigned int*)(ws +  615168);  // 6,400,000
    int*          eidx   = (int*)(ws +  7015168);          // 6,400,000
    int*          noff   = (int*)(ws + 13415168);          // 400,004
    float*        h      = (float*)(ws + 13815424);        // 25,600,000
    float*        scores = (float*)(ws + 39415424);        // 400,000

    hist_kernel        <<<NCHUNK, 1024, 0, stream>>>(dst, cnt);
    chunk_scan_kernel  <<<1, 512, 0, stream>>>(cnt, start, bbase);
    scatter_kernel     <<<NCHUNK, 1024, 0, stream>>>(src, dst, start, pairs);
    bucket_sort_kernel <<<NBUCKET, 1024, 0, stream>>>(pairs, bbase, eidx, noff);
    gather_transform_kernel<<<GT_BLOCKS, 256, 0, stream>>>(
        x, noff, eidx, Wg, bg, Wa, ba, h, scores);
    attn_pool_kernel   <<<N_GRAPHS, POOL_THREADS, 0, stream>>>(h, scores, batch, out);
}

// Round 9
// 218.870 us; speedup vs baseline: 1.6633x; 1.6633x over previous
//
#include <hip/hip_runtime.h>

#define N_NODES  100000
#define N_EDGES  1600000
#define N_GRAPHS 256
#define F        64

#define BSHIFT   8
#define BNODES   256                          // nodes per bucket
#define NBUCKET  391                          // ceil(N_NODES / 256)
#define CHUNK    8192
#define NCHUNK   196                          // ceil(N_EDGES / CHUNK)

// ---------- K1: per-chunk bucket histogram (LDS atomics only) ----------
__global__ __launch_bounds__(1024) void hist_kernel(
        const int* __restrict__ dst, int* __restrict__ cnt) {
    __shared__ int hist[NBUCKET];
    int tid = threadIdx.x;
    for (int b = tid; b < NBUCKET; b += 1024) hist[b] = 0;
    __syncthreads();
    int base = blockIdx.x * CHUNK;
    int end  = min(base + CHUNK, N_EDGES);
    for (int e = base + tid; e < end; e += 1024)
        atomicAdd(&hist[dst[e] >> BSHIFT], 1);
    __syncthreads();
    for (int b = tid; b < NBUCKET; b += 1024)
        cnt[blockIdx.x * NBUCKET + b] = hist[b];
}

// ---------- K2: global slot starts per (chunk,bucket) + bucket bases ----------
__global__ __launch_bounds__(512) void chunk_scan_kernel(
        const int* __restrict__ cnt, int* __restrict__ start, int* __restrict__ bbase) {
    __shared__ int t[512];
    int b = threadIdx.x;
    int tot = 0;
    if (b < NBUCKET)
        for (int c = 0; c < NCHUNK; ++c) tot += cnt[c * NBUCKET + b];  // coalesced
    t[b] = (b < NBUCKET) ? tot : 0;
    __syncthreads();
    #pragma unroll
    for (int o = 1; o < 512; o <<= 1) {           // inclusive scan
        int u = (b >= o) ? t[b - o] : 0;
        __syncthreads();
        t[b] += u;
        __syncthreads();
    }
    if (b < NBUCKET) {
        int base = t[b] - tot;                    // exclusive
        bbase[b] = base;
        if (b == NBUCKET - 1) bbase[NBUCKET] = t[b];
        int run = base;
        for (int c = 0; c < NCHUNK; ++c) {
            start[c * NBUCKET + b] = run;         // coalesced
            run += cnt[c * NBUCKET + b];
        }
    }
}

// ---------- K3: bucket-partitioned scatter of packed (dstLocal<<17 | src) ----------
__global__ __launch_bounds__(1024) void scatter_kernel(
        const int* __restrict__ src, const int* __restrict__ dst,
        const int* __restrict__ start, unsigned int* __restrict__ pairs) {
    __shared__ int cur[NBUCKET];
    int tid = threadIdx.x;
    for (int b = tid; b < NBUCKET; b += 1024)
        cur[b] = start[blockIdx.x * NBUCKET + b];
    __syncthreads();
    int base = blockIdx.x * CHUNK;
    int end  = min(base + CHUNK, N_EDGES);
    for (int e = base + tid; e < end; e += 1024) {
        int d = dst[e];
        int slot = atomicAdd(&cur[d >> BSHIFT], 1);
        pairs[slot] = ((unsigned)(d & (BNODES - 1)) << 17) | (unsigned)src[e];
    }
}

// ---------- K4: per-bucket counting sort -> CSR (eidx sorted by dst, noff) ----------
__global__ __launch_bounds__(1024) void bucket_sort_kernel(
        const unsigned int* __restrict__ pairs,
        const int* __restrict__ bbase,
        int* __restrict__ eidx, int* __restrict__ noff) {
    __shared__ int cnt[BNODES];
    __shared__ int pref[BNODES];
    __shared__ int cur[BNODES];
    int tid = threadIdx.x;
    int b = blockIdx.x;
    int lo = bbase[b], hi = bbase[b + 1];

    if (tid < BNODES) cnt[tid] = 0;
    __syncthreads();
    for (int e = lo + tid; e < hi; e += 1024)
        atomicAdd(&cnt[pairs[e] >> 17], 1);
    __syncthreads();
    if (tid < BNODES) pref[tid] = cnt[tid];
    __syncthreads();
    #pragma unroll
    for (int o = 1; o < BNODES; o <<= 1) {
        int u = (tid < BNODES && tid >= o) ? pref[tid - o] : 0;
        __syncthreads();
        if (tid < BNODES) pref[tid] += u;
        __syncthreads();
    }
    if (tid < BNODES) {
        int excl = lo + pref[tid] - cnt[tid];
        cur[tid] = excl;
        int node = b * BNODES + tid;
        if (node < N_NODES) noff[node] = excl;
        if (node == N_NODES - 1) noff[N_NODES] = hi;
    }
    __syncthreads();
    for (int e = lo + tid; e < hi; e += 1024) {
        unsigned int p = pairs[e];
        int slot = atomicAdd(&cur[p >> 17], 1);
        eidx[slot] = (int)(p & 0x1FFFFu);   // writes stay in a 16KB L2-resident window
    }
}

// ---------- K5: fused gather + transform + attention pool ----------
// Wave-per-contiguous-25-node-chunk. R6-proven gather (float4, 4 rows/instr) +
// readlane matmul. Softmax uses unshifted exp (shift-invariant ratio); per-wave
// register accumulation of (sum e*h, sum e), flushed by atomics at graph
// boundaries only (~2 flushes/wave). h/scores arrays never materialize.
#define NODES_PER_WAVE 25
#define GT_NWAVES  (N_NODES / NODES_PER_WAVE)   // 4000
#define GT_BLOCKS  (GT_NWAVES / 4)              // 1000

__global__ __launch_bounds__(256, 4) void gather_pool_kernel(
        const float* __restrict__ x,
        const int*   __restrict__ noff,
        const int*   __restrict__ eidx,
        const int*   __restrict__ batch,
        const float* __restrict__ Wg,   // [64,64] (k, f)
        const float* __restrict__ bg,
        const float* __restrict__ Wa,
        const float* __restrict__ ba,
        float*       __restrict__ out_acc,   // [N_GRAPHS, F] accumulated
        float*       __restrict__ denom) {   // [N_GRAPHS]
    int tid  = threadIdx.x;
    int lane = tid & 63;
    int grp  = lane >> 4;   // 0..3: row within a 4-row gather batch
    int c    = lane & 15;   // float4 chunk within a row
    int waveId = blockIdx.x * 4 + (tid >> 6);

    float wcol[F];
    #pragma unroll
    for (int k = 0; k < F; ++k) wcol[k] = Wg[k * F + lane];
    float bgl = bg[lane];
    float wal = Wa[lane];
    float ba0 = ba[0];

    const float4* x4 = (const float4*)x;

    int n0   = waveId * NODES_PER_WAVE;
    int nEnd = n0 + NODES_PER_WAVE;          // N_NODES % 25 == 0

    int   cur_g = batch[n0];
    float accw  = 0.f;   // per-lane: sum e * h[lane]
    float denw  = 0.f;   // replicated: sum e

    for (int n = n0; n < nEnd; ++n) {
        int start = noff[n];
        int end   = noff[n + 1];

        float4 a = make_float4(0.f, 0.f, 0.f, 0.f);
        for (int base = start; base < end; base += 64) {
            int jmax = end - base; if (jmax > 64) jmax = 64;
            int sl = (base + lane < end) ? eidx[base + lane] : 0;   // coalesced
            for (int j = 0; j < jmax; j += 4) {
                int el = j + grp;
                int s  = __shfl(sl, el, 64);
                if (el < jmax) {
                    float4 v = x4[s * 16 + c];   // 4 rows / wave-instruction
                    a.x += v.x; a.y += v.y; a.z += v.z; a.w += v.w;
                }
            }
        }
        #pragma unroll
        for (int o = 16; o <= 32; o <<= 1) {
            a.x += __shfl_xor(a.x, o, 64);
            a.y += __shfl_xor(a.y, o, 64);
            a.z += __shfl_xor(a.z, o, 64);
            a.w += __shfl_xor(a.w, o, 64);
        }
        { float4 v = x4[n * 16 + c]; a.x += v.x; a.y += v.y; a.z += v.z; a.w += v.w; }

        float re[4] = {a.x, a.y, a.z, a.w};
        float acc0 = 0.f, acc1 = 0.f, acc2 = 0.f, acc3 = 0.f;
        #pragma unroll
        for (int k = 0; k < F; k += 4) {
            float r0 = __int_as_float(__builtin_amdgcn_readlane(__float_as_int(re[0]), k >> 2));
            float r1 = __int_as_float(__builtin_amdgcn_readlane(__float_as_int(re[1]), k >> 2));
            float r2 = __int_as_float(__builtin_amdgcn_readlane(__float_as_int(re[2]), k >> 2));
            float r3 = __int_as_float(__builtin_amdgcn_readlane(__float_as_int(re[3]), k >> 2));
            acc0 += r0 * wcol[k + 0];
            acc1 += r1 * wcol[k + 1];
            acc2 += r2 * wcol[k + 2];
            acc3 += r3 * wcol[k + 3];
        }
        float hv = (acc0 + acc1) + (acc2 + acc3) + bgl;
        hv = hv > 0.f ? hv : 0.f;

        float p = hv * wal;
        #pragma unroll
        for (int o = 32; o > 0; o >>= 1)
            p += __shfl_down(p, o, 64);
        float s = __int_as_float(__builtin_amdgcn_readlane(__float_as_int(p), 0)) + ba0;
        float e = __expf(s);    // unshifted: softmax ratio is shift-invariant

        int g = batch[n];       // wave-uniform
        if (g != cur_g) {
            atomicAdd(&out_acc[cur_g * F + lane], accw);
            if (lane == 0) atomicAdd(&denom[cur_g], denw);
            accw = 0.f; denw = 0.f; cur_g = g;
        }
        accw += e * hv;
        denw += e;
    }
    atomicAdd(&out_acc[cur_g * F + lane], accw);
    if (lane == 0) atomicAdd(&denom[cur_g], denw);
}

// ---------- K6: out /= denom ----------
__global__ __launch_bounds__(256) void finalize_kernel(
        float* __restrict__ out, const float* __restrict__ denom) {
    int i = blockIdx.x * 256 + threadIdx.x;
    if (i >= N_GRAPHS * F) return;
    float d = denom[i >> 6];
    out[i] = (d > 0.f) ? out[i] / d : 0.f;
}

extern "C" void kernel_launch(void* const* d_in, const int* in_sizes, int n_in,
                              void* d_out, int out_size, void* d_ws, size_t ws_size,
                              hipStream_t stream) {
    const float* x     = (const float*)d_in[0];
    const int*   ei    = (const int*)d_in[1];   // [2, N_EDGES]
    const int*   batch = (const int*)d_in[2];   // [N_NODES]
    const float* Wg    = (const float*)d_in[3];
    const float* bg    = (const float*)d_in[4];
    const float* Wa    = (const float*)d_in[5];
    const float* ba    = (const float*)d_in[6];
    float* out = (float*)d_out;

    const int* src = ei;
    const int* dst = ei + N_EDGES;

    // workspace layout (bytes, 256-aligned)
    char* ws = (char*)d_ws;
    int*          cnt    = (int*)(ws);                     // 306,544
    int*          start  = (int*)(ws +   306688);          // 306,544
    int*          bbase  = (int*)(ws +   613376);          // 1,568
    unsigned int* pairs  = (unsigned int*)(ws +  615168);  // 6,400,000
    int*          eidx   = (int*)(ws +  7015168);          // 6,400,000
    int*          noff   = (int*)(ws + 13415168);          // 400,004
    float*        denom  = (float*)(ws + 13815424);        // 1,024

    hipMemsetAsync(out,   0, (size_t)N_GRAPHS * F * sizeof(float), stream);
    hipMemsetAsync(denom, 0, N_GRAPHS * sizeof(float), stream);

    hist_kernel        <<<NCHUNK, 1024, 0, stream>>>(dst, cnt);
    chunk_scan_kernel  <<<1, 512, 0, stream>>>(cnt, start, bbase);
    scatter_kernel     <<<NCHUNK, 1024, 0, stream>>>(src, dst, start, pairs);
    bucket_sort_kernel <<<NBUCKET, 1024, 0, stream>>>(pairs, bbase, eidx, noff);
    gather_pool_kernel <<<GT_BLOCKS, 256, 0, stream>>>(
        x, noff, eidx, batch, Wg, bg, Wa, ba, out, denom);
    finalize_kernel    <<<(N_GRAPHS * F + 255) / 256, 256, 0, stream>>>(out, denom);
}